// Round 1
// baseline (274.668 us; speedup 1.0000x reference)
//
#include <hip/hip_runtime.h>

// GroupBatchNorm: B=512, C=65536, G=4096, fp32 in/out.
// Memory-bound: ~384 MiB min traffic -> ~61 us floor @ 6.3 TB/s.
//
// R4 pipeline (attacks R3's latency-bound colsum @ 1.1 TB/s, 33 MB atomic
// write churn):
//   zero_k   : zero the 3G group accumulators (48 KB)
//   colsum_k : per-channel partial sum/sumsq over 32 batch chunks.
//              8 float4 loads batched into registers for ILP (8 KB/wave in
//              flight), partials stored as plain float4 (NO atomics).
//   gsum_k   : reduce partials over chunks (coalesced), atomic scatter into
//              per-group accumulators (196K atomics over 12K addresses).
//   cfinal_k : per-channel fused scale/shift (group finalize recomputed
//              inline -- 16x redundant rsqrt, saves a kernel launch)
//   norm_k   : one float4 per thread: out = x*cscale[c] + cshift[c]

constexpr int B = 512;
constexpr int C = 65536;
constexpr int G = 4096;
constexpr int SPLIT = 32;         // batch chunks for stage-1 parallelism
constexpr int ROWS = B / SPLIT;   // 16 rows per chunk
constexpr int BATCH = 8;          // loads in flight per thread
#define EPS 1e-5f

// Device-global scratch (allocated at module load; no d_ws dependence).
__device__ float g_part1[SPLIT * C];   // 8 MB  per-chunk channel sums
__device__ float g_part2[SPLIT * C];   // 8 MB  per-chunk channel sumsq
__device__ float g_gsum[G];
__device__ float g_gsum2[G];
__device__ float g_gcnt[G];
__device__ float g_cscale[C];
__device__ float g_cshift[C];

__global__ __launch_bounds__(256) void zero_k() {
    int i = blockIdx.x * 256 + threadIdx.x;
    if (i < G) {
        g_gsum[i] = 0.0f;
        g_gsum2[i] = 0.0f;
        g_gcnt[i] = 0.0f;
    }
}

// Stage 1: thread owns 4 consecutive channels (one float4/row); 16 rows in
// two batches of 8 register-buffered loads. grid = (C/1024)*SPLIT = 2048.
__global__ __launch_bounds__(256) void colsum_k(const float* __restrict__ x) {
    const int nblk_c = C / 1024;                               // 64
    const int c4 = (blockIdx.x % nblk_c) * 256 + threadIdx.x;  // channel-quad
    const int chunk = blockIdx.x / nblk_c;
    const float4* __restrict__ xp =
        (const float4*)(x + (size_t)chunk * ROWS * C) + c4;
    float4 s = {0.f, 0.f, 0.f, 0.f};
    float4 s2 = {0.f, 0.f, 0.f, 0.f};
    float4 vbuf[BATCH];
    for (int base = 0; base < ROWS; base += BATCH) {
#pragma unroll
        for (int j = 0; j < BATCH; ++j)
            vbuf[j] = xp[(size_t)(base + j) * (C / 4)];
#pragma unroll
        for (int j = 0; j < BATCH; ++j) {
            float4 v = vbuf[j];
            s.x += v.x; s.y += v.y; s.z += v.z; s.w += v.w;
            s2.x = fmaf(v.x, v.x, s2.x);
            s2.y = fmaf(v.y, v.y, s2.y);
            s2.z = fmaf(v.z, v.z, s2.z);
            s2.w = fmaf(v.w, v.w, s2.w);
        }
    }
    ((float4*)g_part1)[(size_t)chunk * (C / 4) + c4] = s;
    ((float4*)g_part2)[(size_t)chunk * (C / 4) + c4] = s2;
}

// Stage 2: per-channel reduction over chunks, then group atomic scatter.
__global__ __launch_bounds__(256) void gsum_k(const int* __restrict__ cg) {
    const int c = blockIdx.x * 256 + threadIdx.x;
    float s = 0.f, s2 = 0.f;
#pragma unroll 8
    for (int k = 0; k < SPLIT; ++k) {
        s += g_part1[(size_t)k * C + c];
        s2 += g_part2[(size_t)k * C + c];
    }
    const int g = cg[c];
    atomicAdd(&g_gsum[g], s);
    atomicAdd(&g_gsum2[g], s2);
    atomicAdd(&g_gcnt[g], 1.0f);
}

// Stage 3: per-channel fused scale/shift (group math recomputed inline).
__global__ __launch_bounds__(256) void cfinal_k(const int* __restrict__ cg,
                                                const float* __restrict__ gamma,
                                                const float* __restrict__ beta) {
    const int c = blockIdx.x * 256 + threadIdx.x;
    const int g = cg[c];
    float cnt = fmaxf(g_gcnt[g] * (float)B, 1.0f);
    float mean = g_gsum[g] / cnt;
    float var = g_gsum2[g] / cnt - mean * mean;
    float inv = 1.0f / sqrtf(var + EPS);
    float sc = gamma[g] * inv;
    g_cscale[c] = sc;
    g_cshift[c] = fmaf(-mean, sc, beta[g]);
}

// Stage 4: streaming normalize, exactly one float4 per thread.
// grid = B*C/4/256 = 32768 blocks.
__global__ __launch_bounds__(256) void norm_k(const float* __restrict__ x,
                                              float* __restrict__ out) {
    const size_t i = (size_t)blockIdx.x * 256 + threadIdx.x;
    const int c4 = (int)(i & (C / 4 - 1));  // channel-quad (C/4 pow2)
    float4 xv = ((const float4*)x)[i];
    float4 s = ((const float4*)g_cscale)[c4];
    float4 t = ((const float4*)g_cshift)[c4];
    float4 o;
    o.x = fmaf(xv.x, s.x, t.x);
    o.y = fmaf(xv.y, s.y, t.y);
    o.z = fmaf(xv.z, s.z, t.z);
    o.w = fmaf(xv.w, s.w, t.w);
    ((float4*)out)[i] = o;
}

extern "C" void kernel_launch(void* const* d_in, const int* in_sizes, int n_in,
                              void* d_out, int out_size, void* d_ws, size_t ws_size,
                              hipStream_t stream) {
    const float* x = (const float*)d_in[0];
    const int* cg = (const int*)d_in[1];
    const float* gamma = (const float*)d_in[2];
    const float* beta = (const float*)d_in[3];
    float* out = (float*)d_out;
    (void)d_ws; (void)ws_size; (void)in_sizes; (void)n_in; (void)out_size;

    zero_k<<<(G + 255) / 256, 256, 0, stream>>>();
    colsum_k<<<(C / 1024) * SPLIT, 256, 0, stream>>>(x);
    gsum_k<<<C / 256, 256, 0, stream>>>(cg);
    cfinal_k<<<C / 256, 256, 0, stream>>>(cg, gamma, beta);
    norm_k<<<(B * C / 4) / 256, 256, 0, stream>>>(x, out);
}